// Round 1
// baseline (4002.731 us; speedup 1.0000x reference)
//
#include <hip/hip_runtime.h>

#define BB 4
#define CC 64
#define TT 800
#define FF 65
#define EE 8
#define CVV 16
#define HH 4
#define DQK (EE*FF)   // 520
#define DV (CVV*FF)   // 1040

// ---------------- K0: x = concat(pos, neg) + seg ----------------
__global__ __launch_bounds__(256) void buildx_kernel(
    const float* __restrict__ pos, const float* __restrict__ neg,
    const float* __restrict__ seg, float* __restrict__ X)
{
  size_t i = (size_t)blockIdx.x * 256 + threadIdx.x;
  const size_t total = (size_t)BB * CC * TT * FF;
  if (i >= total) return;
  int f = (int)(i % FF);
  size_t r = i / FF;
  int t = (int)(r % TT);
  size_t r2 = r / TT;
  int c = (int)(r2 % CC);
  int b = (int)(r2 / CC);
  float v; int si;
  if (t < 400) { v = pos[(((size_t)b * CC + c) * 400 + t) * FF + f]; si = 0; }
  else         { v = neg[(((size_t)b * CC + c) * 400 + (t - 400)) * FF + f]; si = 1; }
  X[i] = v + seg[(size_t)si * CC * FF + c * FF + f];
}

// ---------------- K1: QKV conv1x1 + PReLU + per-head LN ----------------
__global__ __launch_bounds__(256) void qkv_kernel(
    const float* __restrict__ X,
    const float* __restrict__ Qw, const float* __restrict__ Qb, const float* __restrict__ Qa,
    const float* __restrict__ Qg, const float* __restrict__ Qbe,
    const float* __restrict__ Kw, const float* __restrict__ Kbi, const float* __restrict__ Ka,
    const float* __restrict__ Kg, const float* __restrict__ Kbe,
    const float* __restrict__ Vw, const float* __restrict__ Vb, const float* __restrict__ Va,
    const float* __restrict__ Vg, const float* __restrict__ Vbe,
    float* __restrict__ Qo, float* __restrict__ Ko, float* __restrict__ Vo, int li)
{
  __shared__ float xs[CC * FF];     // 4160
  __shared__ float ys[128 * FF];    // 8320
  __shared__ float gmu[12], grs[12];
  int tid = threadIdx.x;
  int b = blockIdx.x / TT, t = blockIdx.x % TT;
  const float* xp = X + (size_t)b * CC * TT * FF + (size_t)t * FF;
  for (int i = tid; i < CC * FF; i += 256) {
    int c = i / FF, f = i - c * FF;
    xs[i] = xp[(size_t)c * TT * FF + f];
  }
  __syncthreads();
  const float* qw = Qw + (size_t)li * HH * EE * CC;
  const float* kw = Kw + (size_t)li * HH * EE * CC;
  const float* vw = Vw + (size_t)li * HH * CVV * CC;
  // thread -> (oc pair, f quarter): oc0 = p in [0,64) (Q:0-31, K:32-63), oc1 = 64+p (V)
  int p  = tid & 63;
  int fq = tid >> 6;
  int f0 = fq * 16;
  const float* wr0 = (p < 32) ? (qw + p * CC) : (kw + (p - 32) * CC);
  const float* wr1 = vw + p * CC;
  float a0[17], a1[17];
#pragma unroll
  for (int j = 0; j < 17; ++j) { a0[j] = 0.f; a1[j] = 0.f; }
  for (int c = 0; c < CC; ++c) {
    float w0 = wr0[c], w1 = wr1[c];
    const float* xr = &xs[c * FF + f0];
#pragma unroll
    for (int j = 0; j < 17; ++j) {
      float xv = xr[j];
      a0[j] = fmaf(w0, xv, a0[j]);
      a1[j] = fmaf(w1, xv, a1[j]);
    }
  }
  float bias0  = (p < 32) ? Qb[li * HH * EE + p] : Kbi[li * HH * EE + (p - 32)];
  float alpha0 = (p < 32) ? Qa[li * HH + (p >> 3)] : Ka[li * HH + ((p - 32) >> 3)];
  float bias1  = Vb[li * HH * CVV + p];
  float alpha1 = Va[li * HH + (p >> 4)];
  int nf = (fq == 3) ? 17 : 16;
  for (int j = 0; j < nf; ++j) {
    float v0 = a0[j] + bias0; v0 = v0 >= 0.f ? v0 : alpha0 * v0;
    float v1 = a1[j] + bias1; v1 = v1 >= 0.f ? v1 : alpha1 * v1;
    ys[p * FF + f0 + j] = v0;
    ys[(64 + p) * FF + f0 + j] = v1;
  }
  __syncthreads();
  // per-(h) group stats: wave w handles Q head w, K head w, V head w
  int wv = tid >> 6, lane = tid & 63;
  for (int gi = 0; gi < 3; ++gi) {
    int base = (gi == 0) ? (8 * wv) * FF : (gi == 1 ? (32 + 8 * wv) * FF : (64 + 16 * wv) * FF);
    int n = (gi == 2) ? CVV * FF : EE * FF;
    float s = 0.f, ss = 0.f;
    for (int i = lane; i < n; i += 64) { float v = ys[base + i]; s += v; ss += v * v; }
#pragma unroll
    for (int off = 32; off; off >>= 1) { s += __shfl_down(s, off); ss += __shfl_down(ss, off); }
    if (lane == 0) {
      float inv_n = 1.f / n;
      float mu = s * inv_n;
      float var = ss * inv_n - mu * mu;
      gmu[gi * 4 + wv] = mu;
      grs[gi * 4 + wv] = rsqrtf(var + 1e-5f);
    }
  }
  __syncthreads();
  const float* qg  = Qg  + (size_t)li * HH * EE * FF;
  const float* qbe = Qbe + (size_t)li * HH * EE * FF;
  const float* kg2  = Kg  + (size_t)li * HH * EE * FF;
  const float* kbe2 = Kbe + (size_t)li * HH * EE * FF;
  const float* vg2  = Vg  + (size_t)li * HH * CVV * FF;
  const float* vbe2 = Vbe + (size_t)li * HH * CVV * FF;
  for (int item = tid; item < 128 * FF; item += 256) {
    int oc = item / FF, f = item - oc * FF;
    float v = ys[item];
    if (oc < 32) {
      int g = oc >> 3;
      float o = (v - gmu[g]) * grs[g] * qg[item] + qbe[item];
      int h = oc >> 3, e = oc & 7;
      Qo[((((size_t)h * BB + b) * TT + t) * EE + e) * FF + f] = o;
    } else if (oc < 64) {
      int ok = oc - 32; int g = 4 + (ok >> 3);
      float o = (v - gmu[g]) * grs[g] * kg2[ok * FF + f] + kbe2[ok * FF + f];
      int h = ok >> 3, e = ok & 7;
      Ko[((((size_t)h * BB + b) * TT + t) * EE + e) * FF + f] = o;
    } else {
      int ov = oc - 64; int g = 8 + (ov >> 4);
      float o = (v - gmu[g]) * grs[g] * vg2[ov * FF + f] + vbe2[ov * FF + f];
      int h = ov >> 4, cv = ov & 15;
      Vo[((((size_t)h * BB + b) * TT + t) * CVV + cv) * FF + f] = o;
    }
  }
}

// ---------------- K2: S = Q @ K^T * scale  (per h,b; 64x64 tiles) ----------------
__global__ __launch_bounds__(256) void qk_kernel(
    const float* __restrict__ Qb_, const float* __restrict__ Kb_, float* __restrict__ S)
{
  __shared__ __align__(16) float Qt[65][68];
  __shared__ __align__(16) float Kt[65][68];
  int mt = blockIdx.x, nt = blockIdx.y, z = blockIdx.z;
  const float* Qp = Qb_ + (size_t)z * TT * DQK;
  const float* Kp = Kb_ + (size_t)z * TT * DQK;
  float* Sp = S + (size_t)z * TT * TT;
  int m0 = mt * 64, n0 = nt * 64;
  int tx = threadIdx.x & 15, ty = threadIdx.x >> 4;
  int ty4 = ty * 4, tx4 = tx * 4;
  float acc[4][4] = {};
  for (int kc = 0; kc < 8; ++kc) {
    for (int idx = threadIdx.x; idx < 64 * 65; idx += 256) {
      int r = idx / 65, cc2 = idx - r * 65;
      int m = m0 + r;
      Qt[cc2][r] = (m < TT) ? Qp[(size_t)m * DQK + kc * 65 + cc2] : 0.f;
      int n = n0 + r;
      Kt[cc2][r] = (n < TT) ? Kp[(size_t)n * DQK + kc * 65 + cc2] : 0.f;
    }
    __syncthreads();
    for (int cc2 = 0; cc2 < 65; ++cc2) {
      float4 q = *(const float4*)&Qt[cc2][ty4];
      float4 k = *(const float4*)&Kt[cc2][tx4];
      float qa[4] = {q.x, q.y, q.z, q.w};
      float ka[4] = {k.x, k.y, k.z, k.w};
#pragma unroll
      for (int i = 0; i < 4; ++i)
#pragma unroll
        for (int j = 0; j < 4; ++j)
          acc[i][j] = fmaf(qa[i], ka[j], acc[i][j]);
    }
    __syncthreads();
  }
  const float scale = 0.04385290096535146f;  // 1/sqrt(520)
#pragma unroll
  for (int i = 0; i < 4; ++i)
#pragma unroll
    for (int j = 0; j < 4; ++j) {
      int m = m0 + ty4 + i, n = n0 + tx4 + j;
      if (m < TT && n < TT) Sp[(size_t)m * TT + n] = acc[i][j] * scale;
    }
}

// ---------------- K3: row softmax over S rows of 800 ----------------
__global__ __launch_bounds__(256) void softmax_kernel(float* __restrict__ S)
{
  float* p = S + (size_t)blockIdx.x * TT;
  int tid = threadIdx.x;
  __shared__ float red[8];
  float mx = -1e30f;
  for (int i = tid; i < TT; i += 256) mx = fmaxf(mx, p[i]);
#pragma unroll
  for (int off = 32; off; off >>= 1) mx = fmaxf(mx, __shfl_down(mx, off));
  int wv = tid >> 6, lane = tid & 63;
  if (lane == 0) red[wv] = mx;
  __syncthreads();
  mx = fmaxf(fmaxf(red[0], red[1]), fmaxf(red[2], red[3]));
  float sum = 0.f;
  for (int i = tid; i < TT; i += 256) { float e = __expf(p[i] - mx); p[i] = e; sum += e; }
#pragma unroll
  for (int off = 32; off; off >>= 1) sum += __shfl_down(sum, off);
  if (lane == 0) red[4 + wv] = sum;
  __syncthreads();
  sum = red[4] + red[5] + red[6] + red[7];
  float inv = 1.0f / sum;
  for (int i = tid; i < TT; i += 256) p[i] *= inv;
}

// ---------------- K4: O = P @ V  (per h,b), write O in [B,C,T,F] ----------------
__global__ __launch_bounds__(256) void pv_kernel(
    const float* __restrict__ S, const float* __restrict__ Vb_, float* __restrict__ O)
{
  __shared__ __align__(16) float Pt[32][68];
  __shared__ __align__(16) float Vt[32][68];
  int mt = blockIdx.x, nt = blockIdx.y, z = blockIdx.z;
  int h = z >> 2, b = z & 3;
  const float* Sp = S + (size_t)z * TT * TT;
  const float* Vp = Vb_ + (size_t)z * TT * DV;
  int m0 = mt * 64, n0 = nt * 64;
  int tx = threadIdx.x & 15, ty = threadIdx.x >> 4;
  int ty4 = ty * 4, tx4 = tx * 4;
  float acc[4][4] = {};
  for (int kc = 0; kc < 25; ++kc) {
    int k0 = kc * 32;
    for (int idx = threadIdx.x; idx < 64 * 32; idx += 256) {
      int i = idx >> 5, kk = idx & 31;
      int m = m0 + i;
      Pt[kk][i] = (m < TT) ? Sp[(size_t)m * TT + k0 + kk] : 0.f;
    }
    for (int idx = threadIdx.x; idx < 32 * 64; idx += 256) {
      int kk = idx >> 6, j = idx & 63;
      int n = n0 + j;
      Vt[kk][j] = (n < DV) ? Vp[(size_t)(k0 + kk) * DV + n] : 0.f;
    }
    __syncthreads();
    for (int kk = 0; kk < 32; ++kk) {
      float4 pq = *(const float4*)&Pt[kk][ty4];
      float4 vv = *(const float4*)&Vt[kk][tx4];
      float pa[4] = {pq.x, pq.y, pq.z, pq.w};
      float va[4] = {vv.x, vv.y, vv.z, vv.w};
#pragma unroll
      for (int i = 0; i < 4; ++i)
#pragma unroll
        for (int j = 0; j < 4; ++j)
          acc[i][j] = fmaf(pa[i], va[j], acc[i][j]);
    }
    __syncthreads();
  }
#pragma unroll
  for (int i = 0; i < 4; ++i)
#pragma unroll
    for (int j = 0; j < 4; ++j) {
      int m = m0 + ty4 + i, n = n0 + tx4 + j;
      if (m < TT && n < DV) {
        int cv = n / 65, f = n - cv * 65;
        O[(((size_t)b * CC + h * CVV + cv) * TT + m) * FF + f] = acc[i][j];
      }
    }
}

// ---------------- K5: P-proj conv1x1 + PReLU + LN + optional residual ----------------
__global__ __launch_bounds__(256) void pproj_kernel(
    const float* __restrict__ O, const float* __restrict__ Pw, const float* __restrict__ Pb,
    const float* __restrict__ Pa, const float* __restrict__ Pg, const float* __restrict__ Pbe,
    const float* __restrict__ Xin, float* __restrict__ Xout, int li, int residual)
{
  __shared__ float os[CC * FF];
  __shared__ float ys[CC * FF];
  __shared__ float redbuf[8];
  __shared__ float stats[2];
  int tid = threadIdx.x;
  int b = blockIdx.x / TT, t = blockIdx.x % TT;
  const float* op = O + (size_t)b * CC * TT * FF + (size_t)t * FF;
  for (int i = tid; i < CC * FF; i += 256) {
    int c = i / FF, f = i - c * FF;
    os[i] = op[(size_t)c * TT * FF + f];
  }
  __syncthreads();
  const float* pw = Pw + li * CC * CC;
  int oc = tid & 63, fq = tid >> 6, f0 = fq * 16;
  float a[17];
#pragma unroll
  for (int j = 0; j < 17; ++j) a[j] = 0.f;
  for (int c = 0; c < CC; ++c) {
    float w = pw[oc * CC + c];
    const float* xr = &os[c * FF + f0];
#pragma unroll
    for (int j = 0; j < 17; ++j) a[j] = fmaf(w, xr[j], a[j]);
  }
  float bias = Pb[li * CC + oc], alpha = Pa[li];
  int nf = (fq == 3) ? 17 : 16;
  for (int j = 0; j < nf; ++j) {
    float v = a[j] + bias; v = v >= 0.f ? v : alpha * v;
    ys[oc * FF + f0 + j] = v;
  }
  __syncthreads();
  float s = 0.f, ss = 0.f;
  for (int i = tid; i < CC * FF; i += 256) { float v = ys[i]; s += v; ss += v * v; }
#pragma unroll
  for (int off = 32; off; off >>= 1) { s += __shfl_down(s, off); ss += __shfl_down(ss, off); }
  int wv = tid >> 6, lane = tid & 63;
  if (lane == 0) { redbuf[wv] = s; redbuf[4 + wv] = ss; }
  __syncthreads();
  if (tid == 0) {
    float st  = redbuf[0] + redbuf[1] + redbuf[2] + redbuf[3];
    float sst = redbuf[4] + redbuf[5] + redbuf[6] + redbuf[7];
    const float inv_n = 1.f / (CC * FF);
    float mu = st * inv_n;
    float var = sst * inv_n - mu * mu;
    stats[0] = mu; stats[1] = rsqrtf(var + 1e-5f);
  }
  __syncthreads();
  float mu = stats[0], rstd = stats[1];
  const float* pg  = Pg  + (size_t)li * CC * FF;
  const float* pbe = Pbe + (size_t)li * CC * FF;
  const float* xp = Xin + (size_t)b * CC * TT * FF + (size_t)t * FF;
  float* xo = Xout + (size_t)b * CC * TT * FF + (size_t)t * FF;
  for (int i = tid; i < CC * FF; i += 256) {
    int c = i / FF, f = i - c * FF;
    float v = (ys[i] - mu) * rstd * pg[i] + pbe[i];
    if (residual) v += xp[(size_t)c * TT * FF + f];
    xo[(size_t)c * TT * FF + f] = v;
  }
}

extern "C" void kernel_launch(void* const* d_in, const int* in_sizes, int n_in,
                              void* d_out, int out_size, void* d_ws, size_t ws_size,
                              hipStream_t stream) {
  const float* pos = (const float*)d_in[0];
  const float* neg = (const float*)d_in[1];
  const float* seg = (const float*)d_in[2];
  const float* Qw  = (const float*)d_in[3];
  const float* Qb  = (const float*)d_in[4];
  const float* Qa  = (const float*)d_in[5];
  const float* Qg  = (const float*)d_in[6];
  const float* Qbe = (const float*)d_in[7];
  const float* Kw  = (const float*)d_in[8];
  const float* Kbi = (const float*)d_in[9];
  const float* Ka  = (const float*)d_in[10];
  const float* Kg  = (const float*)d_in[11];
  const float* Kbe = (const float*)d_in[12];
  const float* Vw  = (const float*)d_in[13];
  const float* Vb  = (const float*)d_in[14];
  const float* Va  = (const float*)d_in[15];
  const float* Vg  = (const float*)d_in[16];
  const float* Vbe = (const float*)d_in[17];
  const float* Pw  = (const float*)d_in[18];
  const float* Pb  = (const float*)d_in[19];
  const float* Pa  = (const float*)d_in[20];
  const float* Pg  = (const float*)d_in[21];
  const float* Pbe = (const float*)d_in[22];
  float* out = (float*)d_out;
  float* ws = (float*)d_ws;

  const size_t XN = (size_t)BB * CC * TT * FF;   // 13,312,000
  const size_t QN = (size_t)HH * BB * TT * DQK;  //  6,656,000
  float* X    = ws;
  float* Vbuf = X + XN;
  float* Qbuf = Vbuf + XN;
  float* Kbuf = Qbuf + QN;
  float* Obuf = Qbuf;          // O aliases Q∪K (dead after qk_kernel)
  float* Sbuf = Kbuf + QN;     // 10,240,000 floats

  dim3 blk(256);
  buildx_kernel<<<(unsigned)((XN + 255) / 256), blk, 0, stream>>>(pos, neg, seg, X);
  for (int li = 0; li < 4; ++li) {
    qkv_kernel<<<BB * TT, blk, 0, stream>>>(X, Qw, Qb, Qa, Qg, Qbe,
                                            Kw, Kbi, Ka, Kg, Kbe,
                                            Vw, Vb, Va, Vg, Vbe,
                                            Qbuf, Kbuf, Vbuf, li);
    qk_kernel<<<dim3(13, 13, 16), blk, 0, stream>>>(Qbuf, Kbuf, Sbuf);
    softmax_kernel<<<HH * BB * TT, blk, 0, stream>>>(Sbuf);
    pv_kernel<<<dim3(13, 17, 16), blk, 0, stream>>>(Sbuf, Vbuf, Obuf);
    pproj_kernel<<<BB * TT, blk, 0, stream>>>(Obuf, Pw, Pb, Pa, Pg, Pbe,
                                              X, (li == 3) ? out : X, li,
                                              (li == 0) ? 1 : 0);
  }
}

// Round 2
// 2022.230 us; speedup vs baseline: 1.9794x; 1.9794x over previous
//
#include <hip/hip_runtime.h>

#define BB 4
#define CC 64
#define TT 800
#define FF 65
#define EE 8
#define CVV 16
#define HH 4

typedef __attribute__((ext_vector_type(8))) short short8;
typedef __attribute__((ext_vector_type(4))) float f32x4;

__device__ __forceinline__ float bf2f(unsigned short u) {
  unsigned v = ((unsigned)u) << 16;
  return __builtin_bit_cast(float, v);
}
__device__ __forceinline__ unsigned short f2bf(float f) {
  unsigned u = __builtin_bit_cast(unsigned, f);
  unsigned r = (u + 0x7fffu + ((u >> 16) & 1u)) >> 16;
  return (unsigned short)r;
}

// ---------------- zero ----------------
__global__ __launch_bounds__(256) void zero_kernel(float4* __restrict__ p, size_t n16) {
  size_t i = (size_t)blockIdx.x * 256 + threadIdx.x;
  size_t stride = (size_t)gridDim.x * 256;
  float4 z = {0.f, 0.f, 0.f, 0.f};
  for (; i < n16; i += stride) p[i] = z;
}

// ---------------- K0: x = concat(pos, neg) + seg ----------------
__global__ __launch_bounds__(256) void buildx_kernel(
    const float* __restrict__ pos, const float* __restrict__ neg,
    const float* __restrict__ seg, float* __restrict__ X)
{
  size_t i = (size_t)blockIdx.x * 256 + threadIdx.x;
  const size_t total = (size_t)BB * CC * TT * FF;
  if (i >= total) return;
  int f = (int)(i % FF);
  size_t r = i / FF;
  int t = (int)(r % TT);
  size_t r2 = r / TT;
  int c = (int)(r2 % CC);
  int b = (int)(r2 / CC);
  float v; int si;
  if (t < 400) { v = pos[(((size_t)b * CC + c) * 400 + t) * FF + f]; si = 0; }
  else         { v = neg[(((size_t)b * CC + c) * 400 + (t - 400)) * FF + f]; si = 1; }
  X[i] = v + seg[(size_t)si * CC * FF + c * FF + f];
}

// ---------------- K1: QKV conv1x1 + PReLU + per-head LN -> bf16 Q,K,V ----------------
__global__ __launch_bounds__(256) void qkv_kernel(
    const float* __restrict__ X,
    const float* __restrict__ Qw, const float* __restrict__ Qb, const float* __restrict__ Qa,
    const float* __restrict__ Qg, const float* __restrict__ Qbe,
    const float* __restrict__ Kw, const float* __restrict__ Kbi, const float* __restrict__ Ka,
    const float* __restrict__ Kg, const float* __restrict__ Kbe,
    const float* __restrict__ Vw, const float* __restrict__ Vb, const float* __restrict__ Va,
    const float* __restrict__ Vg, const float* __restrict__ Vbe,
    unsigned short* __restrict__ Qo, unsigned short* __restrict__ Ko,
    unsigned short* __restrict__ Vo, int li)
{
  __shared__ float xs[CC * FF];     // 4160
  __shared__ float ys[128 * FF];    // 8320
  __shared__ float gmu[12], grs[12];
  int tid = threadIdx.x;
  int b = blockIdx.x / TT, t = blockIdx.x % TT;
  const float* xp = X + (size_t)b * CC * TT * FF + (size_t)t * FF;
  for (int i = tid; i < CC * FF; i += 256) {
    int c = i / FF, f = i - c * FF;
    xs[i] = xp[(size_t)c * TT * FF + f];
  }
  __syncthreads();
  const float* qw = Qw + (size_t)li * HH * EE * CC;
  const float* kw = Kw + (size_t)li * HH * EE * CC;
  const float* vw = Vw + (size_t)li * HH * CVV * CC;
  int p  = tid & 63;
  int fq = tid >> 6;
  int f0 = fq * 16;
  const float* wr0 = (p < 32) ? (qw + p * CC) : (kw + (p - 32) * CC);
  const float* wr1 = vw + p * CC;
  float a0[17], a1[17];
#pragma unroll
  for (int j = 0; j < 17; ++j) { a0[j] = 0.f; a1[j] = 0.f; }
  for (int c = 0; c < CC; ++c) {
    float w0 = wr0[c], w1 = wr1[c];
    const float* xr = &xs[c * FF + f0];
#pragma unroll
    for (int j = 0; j < 17; ++j) {
      float xv = xr[j];
      a0[j] = fmaf(w0, xv, a0[j]);
      a1[j] = fmaf(w1, xv, a1[j]);
    }
  }
  float bias0  = (p < 32) ? Qb[li * HH * EE + p] : Kbi[li * HH * EE + (p - 32)];
  float alpha0 = (p < 32) ? Qa[li * HH + (p >> 3)] : Ka[li * HH + ((p - 32) >> 3)];
  float bias1  = Vb[li * HH * CVV + p];
  float alpha1 = Va[li * HH + (p >> 4)];
  int nf = (fq == 3) ? 17 : 16;
  for (int j = 0; j < nf; ++j) {
    float v0 = a0[j] + bias0; v0 = v0 >= 0.f ? v0 : alpha0 * v0;
    float v1 = a1[j] + bias1; v1 = v1 >= 0.f ? v1 : alpha1 * v1;
    ys[p * FF + f0 + j] = v0;
    ys[(64 + p) * FF + f0 + j] = v1;
  }
  __syncthreads();
  int wv = tid >> 6, lane = tid & 63;
  for (int gi = 0; gi < 3; ++gi) {
    int base = (gi == 0) ? (8 * wv) * FF : (gi == 1 ? (32 + 8 * wv) * FF : (64 + 16 * wv) * FF);
    int n = (gi == 2) ? CVV * FF : EE * FF;
    float s = 0.f, ss = 0.f;
    for (int i = lane; i < n; i += 64) { float v = ys[base + i]; s += v; ss += v * v; }
#pragma unroll
    for (int off = 32; off; off >>= 1) { s += __shfl_down(s, off); ss += __shfl_down(ss, off); }
    if (lane == 0) {
      float inv_n = 1.f / n;
      float mu = s * inv_n;
      float var = ss * inv_n - mu * mu;
      gmu[gi * 4 + wv] = mu;
      grs[gi * 4 + wv] = rsqrtf(var + 1e-5f);
    }
  }
  __syncthreads();
  const float* qg   = Qg  + (size_t)li * HH * EE * FF;
  const float* qbe  = Qbe + (size_t)li * HH * EE * FF;
  const float* kg2  = Kg  + (size_t)li * HH * EE * FF;
  const float* kbe2 = Kbe + (size_t)li * HH * EE * FF;
  const float* vg2  = Vg  + (size_t)li * HH * CVV * FF;
  const float* vbe2 = Vbe + (size_t)li * HH * CVV * FF;
  for (int item = tid; item < 128 * FF; item += 256) {
    int oc = item / FF, f = item - oc * FF;
    float v = ys[item];
    if (oc < 32) {
      int g = oc >> 3;
      float o = (v - gmu[g]) * grs[g] * qg[item] + qbe[item];
      int h = oc >> 3, e = oc & 7;
      Qo[((size_t)(h * BB + b) * 896 + t) * 576 + e * 65 + f] = f2bf(o);
    } else if (oc < 64) {
      int ok = oc - 32; int g = 4 + (ok >> 3);
      float o = (v - gmu[g]) * grs[g] * kg2[ok * FF + f] + kbe2[ok * FF + f];
      int h = ok >> 3, e = ok & 7;
      Ko[((size_t)(h * BB + b) * 896 + t) * 576 + e * 65 + f] = f2bf(o);
    } else {
      int ov = oc - 64; int g = 8 + (ov >> 4);
      float o = (v - gmu[g]) * grs[g] * vg2[ov * FF + f] + vbe2[ov * FF + f];
      int h = ov >> 4, cv = ov & 15;
      Vo[((size_t)(h * BB + b) * 800 + t) * 1040 + cv * 65 + f] = f2bf(o);
    }
  }
  // re-zero Q/K pad columns [520,576) for this row t (O overwrote them last layer)
  for (int i = tid; i < 448; i += 256) {
    int h = i / 112, rem = i % 112;
    int which = rem / 56, c = 520 + (rem % 56);
    unsigned short* dst = which ? Ko : Qo;
    dst[((size_t)(h * BB + b) * 896 + t) * 576 + c] = 0;
  }
}

// ---------------- V transpose: [z][800][1040] -> Vt [z][1152][832] ----------------
__global__ __launch_bounds__(256) void vtrans_kernel(
    const unsigned short* __restrict__ V, unsigned short* __restrict__ Vt)
{
  __shared__ unsigned short tile[64][66];
  int z = blockIdx.z;
  const unsigned short* Vp = V + (size_t)z * 800 * 1040;
  unsigned short* Vtp = Vt + (size_t)z * 1152 * 832;
  int t0 = blockIdx.x * 64, n0 = blockIdx.y * 64;
  int tid = threadIdx.x;
#pragma unroll
  for (int it = 0; it < 16; ++it) {
    int idx = it * 256 + tid;
    int r = idx >> 6, c = idx & 63;       // r: t offset, c: n offset
    int t = t0 + r, n = n0 + c;
    tile[r][c] = (t < 800 && n < 1040) ? Vp[(size_t)t * 1040 + n] : (unsigned short)0;
  }
  __syncthreads();
#pragma unroll
  for (int it = 0; it < 16; ++it) {
    int idx = it * 256 + tid;
    int r = idx >> 6, c = idx & 63;       // r: n offset, c: t offset
    int n = n0 + r, t = t0 + c;
    if (n < 1040) Vtp[(size_t)n * 832 + t] = tile[c][r];
  }
}

// ---------------- shared MFMA GEMM body: C128x128 += A[M,K] * B[N,K]^T ----------------
template <int LDA, int LDB, int KSTEPS>
__device__ __forceinline__ void gemm128(
    const unsigned short* __restrict__ Ag, const unsigned short* __restrict__ Bg,
    int m0, int n0, unsigned short* lA, unsigned short* lB, f32x4 acc[4][4])
{
  const int tid = threadIdx.x;
  const int lane = tid & 63;
  const int wid = tid >> 6;
  const int wm = wid >> 1, wn = wid & 1;

  int r_[4], c8_[4], wb_[4];
#pragma unroll
  for (int q = 0; q < 4; ++q) {
    int idx = q * 256 + tid;
    int row = idx >> 3, c8 = idx & 7;
    r_[q] = row; c8_[q] = c8;
    wb_[q] = row * 64 + ((c8 * 8) ^ ((row & 7) << 3));   // short units, 16B swizzle
  }
  const int fr = lane & 15, fk = lane >> 4;
  const int swz = (lane & 7) << 3;
  int aoff[4][2], boff[4][2];
#pragma unroll
  for (int mf = 0; mf < 4; ++mf)
#pragma unroll
    for (int kk = 0; kk < 2; ++kk) {
      aoff[mf][kk] = (wm * 64 + mf * 16 + fr) * 64 + ((kk * 32 + fk * 8) ^ swz);
      boff[mf][kk] = (wn * 64 + mf * 16 + fr) * 64 + ((kk * 32 + fk * 8) ^ swz);
    }

  uint4 ra[4], rb[4];
#pragma unroll
  for (int q = 0; q < 4; ++q) {
    ra[q] = *(const uint4*)&Ag[(size_t)(m0 + r_[q]) * LDA + c8_[q] * 8];
    rb[q] = *(const uint4*)&Bg[(size_t)(n0 + r_[q]) * LDB + c8_[q] * 8];
  }
  for (int ks = 0; ks < KSTEPS; ++ks) {
    __syncthreads();
#pragma unroll
    for (int q = 0; q < 4; ++q) {
      *(uint4*)&lA[wb_[q]] = ra[q];
      *(uint4*)&lB[wb_[q]] = rb[q];
    }
    __syncthreads();
    if (ks + 1 < KSTEPS) {
      int k0 = (ks + 1) * 64;
#pragma unroll
      for (int q = 0; q < 4; ++q) {
        ra[q] = *(const uint4*)&Ag[(size_t)(m0 + r_[q]) * LDA + k0 + c8_[q] * 8];
        rb[q] = *(const uint4*)&Bg[(size_t)(n0 + r_[q]) * LDB + k0 + c8_[q] * 8];
      }
    }
#pragma unroll
    for (int kk = 0; kk < 2; ++kk) {
      short8 a[4], b[4];
#pragma unroll
      for (int i = 0; i < 4; ++i) {
        a[i] = *(const short8*)&lA[aoff[i][kk]];
        b[i] = *(const short8*)&lB[boff[i][kk]];
      }
#pragma unroll
      for (int i = 0; i < 4; ++i)
#pragma unroll
        for (int j = 0; j < 4; ++j)
          acc[i][j] = __builtin_amdgcn_mfma_f32_16x16x32_bf16(a[i], b[j], acc[i][j], 0, 0, 0);
    }
  }
}

// ---------------- K2: S = Q @ K^T * scale -> bf16 scores ----------------
__global__ __launch_bounds__(256) void qk_mfma_kernel(
    const unsigned short* __restrict__ Q, const unsigned short* __restrict__ K,
    unsigned short* __restrict__ SP)
{
  __shared__ __align__(16) unsigned short lA[128 * 64];
  __shared__ __align__(16) unsigned short lB[128 * 64];
  int z = blockIdx.z;
  const unsigned short* Ag = Q + (size_t)z * 896 * 576;
  const unsigned short* Bg = K + (size_t)z * 896 * 576;
  int m0 = blockIdx.x * 128, n0 = blockIdx.y * 128;
  f32x4 acc[4][4];
#pragma unroll
  for (int i = 0; i < 4; ++i)
#pragma unroll
    for (int j = 0; j < 4; ++j) acc[i][j] = {0.f, 0.f, 0.f, 0.f};
  gemm128<576, 576, 9>(Ag, Bg, m0, n0, lA, lB, acc);
  const int lane = threadIdx.x & 63, wid = threadIdx.x >> 6;
  const int wm = wid >> 1, wn = wid & 1;
  unsigned short* Sp = SP + (size_t)z * 896 * 832;
  const float scale = 0.04385290096535146f;   // 1/sqrt(520)
#pragma unroll
  for (int mf = 0; mf < 4; ++mf)
#pragma unroll
    for (int nf = 0; nf < 4; ++nf) {
      int n = n0 + wn * 64 + nf * 16 + (lane & 15);
      if (n >= 800) continue;
#pragma unroll
      for (int j = 0; j < 4; ++j) {
        int m = m0 + wm * 64 + mf * 16 + (lane >> 4) * 4 + j;
        if (m < 800) Sp[(size_t)m * 832 + n] = f2bf(acc[mf][nf][j] * scale);
      }
    }
}

// ---------------- K3: row softmax, bf16 in place ----------------
__global__ __launch_bounds__(256) void softmax_bf16_kernel(unsigned short* __restrict__ SP)
{
  int row = blockIdx.x;
  int z = row / 800, r = row - z * 800;
  unsigned short* p = SP + (size_t)z * 896 * 832 + (size_t)r * 832;
  int tid = threadIdx.x;
  __shared__ float red[8];
  bool act = tid < 200;
  uint2 pk = make_uint2(0u, 0u);
  if (act) pk = *(const uint2*)(p + tid * 4);
  float v0 = bf2f((unsigned short)(pk.x & 0xffff));
  float v1 = bf2f((unsigned short)(pk.x >> 16));
  float v2 = bf2f((unsigned short)(pk.y & 0xffff));
  float v3 = bf2f((unsigned short)(pk.y >> 16));
  float mx = act ? fmaxf(fmaxf(v0, v1), fmaxf(v2, v3)) : -1e30f;
#pragma unroll
  for (int off = 32; off; off >>= 1) mx = fmaxf(mx, __shfl_down(mx, off));
  int wv = tid >> 6, lane = tid & 63;
  if (lane == 0) red[wv] = mx;
  __syncthreads();
  mx = fmaxf(fmaxf(red[0], red[1]), fmaxf(red[2], red[3]));
  float e0 = __expf(v0 - mx), e1 = __expf(v1 - mx), e2 = __expf(v2 - mx), e3 = __expf(v3 - mx);
  float s = act ? (e0 + e1) + (e2 + e3) : 0.f;
#pragma unroll
  for (int off = 32; off; off >>= 1) s += __shfl_down(s, off);
  if (lane == 0) red[4 + wv] = s;
  __syncthreads();
  float inv = 1.0f / (red[4] + red[5] + red[6] + red[7]);
  if (act) {
    unsigned a = (unsigned)f2bf(e0 * inv) | ((unsigned)f2bf(e1 * inv) << 16);
    unsigned b = (unsigned)f2bf(e2 * inv) | ((unsigned)f2bf(e3 * inv) << 16);
    *(uint2*)(p + tid * 4) = make_uint2(a, b);
  }
}

// ---------------- K4: O = P @ Vt^T -> fp32 [B,C,T,F] ----------------
__global__ __launch_bounds__(256) void pv_mfma_kernel(
    const unsigned short* __restrict__ SP, const unsigned short* __restrict__ Vt,
    float* __restrict__ O)
{
  __shared__ __align__(16) unsigned short lA[128 * 64];
  __shared__ __align__(16) unsigned short lB[128 * 64];
  int z = blockIdx.z;
  const unsigned short* Ag = SP + (size_t)z * 896 * 832;
  const unsigned short* Bg = Vt + (size_t)z * 1152 * 832;
  int m0 = blockIdx.x * 128, n0 = blockIdx.y * 128;
  f32x4 acc[4][4];
#pragma unroll
  for (int i = 0; i < 4; ++i)
#pragma unroll
    for (int j = 0; j < 4; ++j) acc[i][j] = {0.f, 0.f, 0.f, 0.f};
  gemm128<832, 832, 13>(Ag, Bg, m0, n0, lA, lB, acc);
  const int lane = threadIdx.x & 63, wid = threadIdx.x >> 6;
  const int wm = wid >> 1, wn = wid & 1;
  int h = z >> 2, bb = z & 3;
#pragma unroll
  for (int mf = 0; mf < 4; ++mf)
#pragma unroll
    for (int nf = 0; nf < 4; ++nf) {
      int n = n0 + wn * 64 + nf * 16 + (lane & 15);
      if (n >= 1040) continue;
      int cv = n / 65, f = n - cv * 65;
      size_t cbase = ((size_t)bb * CC + h * CVV + cv);
#pragma unroll
      for (int j = 0; j < 4; ++j) {
        int m = m0 + wm * 64 + mf * 16 + (lane >> 4) * 4 + j;
        if (m < 800) O[(cbase * TT + m) * FF + f] = acc[mf][nf][j];
      }
    }
}

// ---------------- K5: P-proj conv1x1 + PReLU + LN + optional residual ----------------
__global__ __launch_bounds__(256) void pproj_kernel(
    const float* __restrict__ O, const float* __restrict__ Pw, const float* __restrict__ Pb,
    const float* __restrict__ Pa, const float* __restrict__ Pg, const float* __restrict__ Pbe,
    const float* __restrict__ Xin, float* __restrict__ Xout, int li, int residual)
{
  __shared__ float os[CC * FF];
  __shared__ float ys[CC * FF];
  __shared__ float redbuf[8];
  __shared__ float stats[2];
  int tid = threadIdx.x;
  int b = blockIdx.x / TT, t = blockIdx.x % TT;
  const float* op = O + (size_t)b * CC * TT * FF + (size_t)t * FF;
  for (int i = tid; i < CC * FF; i += 256) {
    int c = i / FF, f = i - c * FF;
    os[i] = op[(size_t)c * TT * FF + f];
  }
  __syncthreads();
  const float* pw = Pw + li * CC * CC;
  int oc = tid & 63, fq = tid >> 6, f0 = fq * 16;
  float a[17];
#pragma unroll
  for (int j = 0; j < 17; ++j) a[j] = 0.f;
  for (int c = 0; c < CC; ++c) {
    float w = pw[oc * CC + c];
    const float* xr = &os[c * FF + f0];
#pragma unroll
    for (int j = 0; j < 17; ++j) a[j] = fmaf(w, xr[j], a[j]);
  }
  float bias = Pb[li * CC + oc], alpha = Pa[li];
  int nf = (fq == 3) ? 17 : 16;
  for (int j = 0; j < nf; ++j) {
    float v = a[j] + bias; v = v >= 0.f ? v : alpha * v;
    ys[oc * FF + f0 + j] = v;
  }
  __syncthreads();
  float s = 0.f, ss = 0.f;
  for (int i = tid; i < CC * FF; i += 256) { float v = ys[i]; s += v; ss += v * v; }
#pragma unroll
  for (int off = 32; off; off >>= 1) { s += __shfl_down(s, off); ss += __shfl_down(ss, off); }
  int wv = tid >> 6, lane = tid & 63;
  if (lane == 0) { redbuf[wv] = s; redbuf[4 + wv] = ss; }
  __syncthreads();
  if (tid == 0) {
    float st  = redbuf[0] + redbuf[1] + redbuf[2] + redbuf[3];
    float sst = redbuf[4] + redbuf[5] + redbuf[6] + redbuf[7];
    const float inv_n = 1.f / (CC * FF);
    float mu = st * inv_n;
    float var = sst * inv_n - mu * mu;
    stats[0] = mu; stats[1] = rsqrtf(var + 1e-5f);
  }
  __syncthreads();
  float mu = stats[0], rstd = stats[1];
  const float* pg  = Pg  + (size_t)li * CC * FF;
  const float* pbe = Pbe + (size_t)li * CC * FF;
  const float* xp = Xin + (size_t)b * CC * TT * FF + (size_t)t * FF;
  float* xo = Xout + (size_t)b * CC * TT * FF + (size_t)t * FF;
  for (int i = tid; i < CC * FF; i += 256) {
    int c = i / FF, f = i - c * FF;
    float v = (ys[i] - mu) * rstd * pg[i] + pbe[i];
    if (residual) v += xp[(size_t)c * TT * FF + f];
    xo[(size_t)c * TT * FF + f] = v;
  }
}

extern "C" void kernel_launch(void* const* d_in, const int* in_sizes, int n_in,
                              void* d_out, int out_size, void* d_ws, size_t ws_size,
                              hipStream_t stream) {
  const float* pos = (const float*)d_in[0];
  const float* neg = (const float*)d_in[1];
  const float* seg = (const float*)d_in[2];
  const float* Qw  = (const float*)d_in[3];
  const float* Qb  = (const float*)d_in[4];
  const float* Qa  = (const float*)d_in[5];
  const float* Qg  = (const float*)d_in[6];
  const float* Qbe = (const float*)d_in[7];
  const float* Kw  = (const float*)d_in[8];
  const float* Kbi = (const float*)d_in[9];
  const float* Ka  = (const float*)d_in[10];
  const float* Kg  = (const float*)d_in[11];
  const float* Kbe = (const float*)d_in[12];
  const float* Vw  = (const float*)d_in[13];
  const float* Vb  = (const float*)d_in[14];
  const float* Va  = (const float*)d_in[15];
  const float* Vg  = (const float*)d_in[16];
  const float* Vbe = (const float*)d_in[17];
  const float* Pw  = (const float*)d_in[18];
  const float* Pb  = (const float*)d_in[19];
  const float* Pa  = (const float*)d_in[20];
  const float* Pg  = (const float*)d_in[21];
  const float* Pbe = (const float*)d_in[22];
  float* out = (float*)d_out;
  char* base = (char*)d_ws;

  // layout (bytes):
  // X    fp32  [0, 53,248,000)
  // Vt   bf16  [53,248,000, 83,918,848)       16 x 1152 x 832
  // SP   bf16  [83,918,848, 107,773,952)      16 x  896 x 832
  // V    bf16  [107,773,952, 134,397,952)     16 x  800 x 1040
  // Qb   bf16  [134,397,952, 150,913,024)     16 x  896 x 576
  // Kb   bf16  [150,913,024, 167,428,096)     16 x  896 x 576
  // O    fp32  aliases [V..Kb) = 53,248,000 B
  float* X = (float*)base;
  unsigned short* Vt16 = (unsigned short*)(base + 53248000);
  unsigned short* SP16 = (unsigned short*)(base + 83918848);
  unsigned short* V16  = (unsigned short*)(base + 107773952);
  unsigned short* Qb16 = (unsigned short*)(base + 134397952);
  unsigned short* Kb16 = (unsigned short*)(base + 150913024);
  float* O = (float*)(base + 107773952);

  dim3 blk(256);
  const size_t XN = (size_t)BB * CC * TT * FF;
  // zero pad regions once per call: [Vt..V) and [Qb..end)
  zero_kernel<<<2048, blk, 0, stream>>>((float4*)(base + 53248000), 54525952 / 16);
  zero_kernel<<<2048, blk, 0, stream>>>((float4*)(base + 134397952), 33030144 / 16);
  buildx_kernel<<<(unsigned)((XN + 255) / 256), blk, 0, stream>>>(pos, neg, seg, X);
  for (int li = 0; li < 4; ++li) {
    qkv_kernel<<<BB * TT, blk, 0, stream>>>(X, Qw, Qb, Qa, Qg, Qbe,
                                            Kw, Kbi, Ka, Kg, Kbe,
                                            Vw, Vb, Va, Vg, Vbe,
                                            Qb16, Kb16, V16, li);
    vtrans_kernel<<<dim3(13, 17, 16), blk, 0, stream>>>(V16, Vt16);
    qk_mfma_kernel<<<dim3(7, 7, 16), blk, 0, stream>>>(Qb16, Kb16, SP16);
    softmax_bf16_kernel<<<HH * BB * TT, blk, 0, stream>>>(SP16);
    pv_mfma_kernel<<<dim3(7, 9, 16), blk, 0, stream>>>(SP16, Vt16, O);
    pproj_kernel<<<BB * TT, blk, 0, stream>>>(O, Pw, Pb, Pa, Pg, Pbe,
                                              X, (li == 3) ? out : X, li,
                                              (li == 0) ? 1 : 0);
  }
}